// Round 9
// baseline (1920.121 us; speedup 1.0000x reference)
//
#include <hip/hip_runtime.h>
#include <math.h>

typedef unsigned short u16;
typedef unsigned int u32;
typedef unsigned long long u64;
typedef __bf16 bf16x8 __attribute__((ext_vector_type(8)));
typedef float floatx4 __attribute__((ext_vector_type(4)));

#define MFMA16(a, b, c) __builtin_amdgcn_mfma_f32_16x16x32_bf16((a), (b), (c), 0, 0, 0)
#define ALD(p) __hip_atomic_load((p), __ATOMIC_RELAXED, __HIP_MEMORY_SCOPE_AGENT)
#define AST(p, v) __hip_atomic_store((p), (v), __ATOMIC_RELAXED, __HIP_MEMORY_SCOPE_AGENT)

__device__ __forceinline__ float bf2f(u16 u) {
  u32 x = ((u32)u) << 16; float f; __builtin_memcpy(&f, &x, 4); return f;
}
__device__ __forceinline__ u16 f2bf(float f) {
  u32 x; __builtin_memcpy(&x, &f, 4);
  return (u16)((x + 0x7FFFu + ((x >> 16) & 1u)) >> 16);  // RNE
}
__device__ __forceinline__ void store_dual(u16* outp, float v) {
  u32 h = (u32)f2bf(v);
  *(u32*)outp = (h << 16) | h;
}
__device__ __forceinline__ bf16x8 ld8(const u16* p) { return *(const bf16x8*)p; }

__device__ __forceinline__ float wred64(float v) {
#pragma unroll
  for (int off = 32; off > 0; off >>= 1) v += __shfl_down(v, off, 64);
  return v;
}

__device__ __forceinline__ void store_final(u16* outp, float ev, int flag) {
  if (!(ev == ev) || fabsf(ev) > 1e37f) ev = -12345.0f - 1000.0f * (float)flag;
  if (flag) *(float*)outp = ev;
  else outp[0] = f2bf(ev);
}

// ---------------- diagnostics ----------------
__global__ void k_sentinel(u16* outp, float v) {
  if (threadIdx.x == 0 && blockIdx.x == 0) store_dual(outp, v);
}

// ---------------- input dtype detect ----------------
__global__ void k_detect(const u32* __restrict__ raw, int* __restrict__ flag) {
  if (threadIdx.x == 0 && blockIdx.x == 0) {
    int outliers = 0;
    for (int i = 0; i < 64; ++i) {
      u32 lo = raw[i] & 0xFFFFu;
      int e = (int)((lo >> 7) & 0xFF);
      if (e < 100 || e > 150) ++outliers;
    }
    *flag = (outliers > 16) ? 1 : 0;
  }
}

// ---------------- fused dtype-aware convert (24 jobs) ----------------
struct CvtJobs {
  const void* src[24];
  u16* dst[24];
  int n[24];
  int bstart[25];
};
__global__ __launch_bounds__(256) void k_cvt_all(CvtJobs a, const int* __restrict__ flag) {
  const int b = blockIdx.x, tid = threadIdx.x;
  int j = 0;
  while (b >= a.bstart[j + 1]) ++j;
  const int base = (b - a.bstart[j]) * 4096;
  const int n = a.n[j];
  if (*flag) {
    const float* s = (const float*)a.src[j];
    u16* d = a.dst[j];
    for (int i0 = base + tid * 4; i0 < base + 4096 && i0 < n; i0 += 1024) {
      float4 v = *(const float4*)(s + i0);
      u16 o[4] = {f2bf(v.x), f2bf(v.y), f2bf(v.z), f2bf(v.w)};
      __builtin_memcpy(d + i0, o, 8);
    }
  } else {
    const u16* s = (const u16*)a.src[j];
    u16* d = a.dst[j];
    for (int i0 = base + tid * 4; i0 < base + 4096 && i0 < n; i0 += 1024)
      *(uint2*)(d + i0) = *(const uint2*)(s + i0);
  }
}

// ---------------- fused transpose (5 jobs) + rownorm (3 jobs) ----------------
struct MiscJobs {
  const u16* tsrc[5];
  u16* tdst[5];
  int tR[5], tC[5];
  int tbstart[6];   // transpose blocks: [0, tb)
  const u16* rX[3];
  float* rout[3];
  int rrows[3];
  int rbstart[4];   // rownorm blocks, offset by tb
};
__global__ __launch_bounds__(256) void k_misc(MiscJobs a) {
  const int b = blockIdx.x, tid = threadIdx.x;
  if (b < a.tbstart[5]) {
    int j = 0;
    while (b >= a.tbstart[j + 1]) ++j;
    const int base = (b - a.tbstart[j]) * 1024;
    const int R = a.tR[j], C = a.tC[j], tot = R * C;
    const u16* in = a.tsrc[j];
    u16* out = a.tdst[j];
#pragma unroll
    for (int k = 0; k < 4; ++k) {
      int i = base + tid + k * 256;
      if (i < tot) { int r = i / C, c = i - r * C; out[c * R + r] = in[i]; }
    }
  } else {
    const int rb = b - a.tbstart[5];
    int j = 0;
    while (rb >= a.rbstart[j + 1]) ++j;
    const int w = tid >> 6, lane = tid & 63;
    const int row = (rb - a.rbstart[j]) * 4 + w;
    if (row >= a.rrows[j]) return;
    const u16* p = a.rX[j] + (size_t)row * 256 + lane * 4;
    float s = 0.f;
#pragma unroll
    for (int i = 0; i < 4; ++i) { float v = bf2f(p[i]); s += v * v; }
    s = wred64(s);
    if (lane == 0) a.rout[j][row] = rsqrtf(s);
  }
}

// ---------------- preterminal MLP + fused rs_ft ----------------
__global__ __launch_bounds__(256) void k_mlp(
    const u16* __restrict__ X0,
    const u16* __restrict__ w1T, const u16* __restrict__ b1,
    const u16* __restrict__ w2T, const u16* __restrict__ b2,
    const u16* __restrict__ w3T, const u16* __restrict__ b3,
    const u16* __restrict__ w4T, const u16* __restrict__ b4,
    u16* __restrict__ FT, float* __restrict__ rs_ft) {
  __shared__ __align__(16) u16 Y[2][64][264];
  const int tid = threadIdx.x, lane = tid & 63, w = tid >> 6;
  const int m16 = lane & 15, kg = lane >> 4;
  const int rbl = w * 16;
  const int rbg = blockIdx.x * 64 + rbl;
  const floatx4 z4 = {0.f, 0.f, 0.f, 0.f};
  floatx4 acc[16];

#pragma unroll
  for (int ct = 0; ct < 16; ++ct) acc[ct] = z4;
  for (int k0 = 0; k0 < 256; k0 += 32) {
    bf16x8 a = ld8(X0 + (size_t)(rbg + m16) * 256 + k0 + kg * 8);
#pragma unroll
    for (int ct = 0; ct < 16; ++ct)
      acc[ct] = MFMA16(a, ld8(w1T + (ct * 16 + m16) * 256 + k0 + kg * 8), acc[ct]);
  }
#pragma unroll
  for (int ct = 0; ct < 16; ++ct) {
    const int col = ct * 16 + m16;
    const float bv = bf2f(b1[col]);
#pragma unroll
    for (int r = 0; r < 4; ++r)
      Y[0][rbl + kg * 4 + r][col] = f2bf(fmaxf(acc[ct][r] + bv, 0.f));
  }
  __syncthreads();
#pragma unroll
  for (int ct = 0; ct < 16; ++ct) acc[ct] = z4;
  for (int k0 = 0; k0 < 256; k0 += 32) {
    bf16x8 a = *(const bf16x8*)(&Y[0][rbl + m16][k0 + kg * 8]);
#pragma unroll
    for (int ct = 0; ct < 16; ++ct)
      acc[ct] = MFMA16(a, ld8(w2T + (ct * 16 + m16) * 256 + k0 + kg * 8), acc[ct]);
  }
#pragma unroll
  for (int ct = 0; ct < 16; ++ct) {
    const int col = ct * 16 + m16;
    const float bv = bf2f(b2[col]);
#pragma unroll
    for (int r = 0; r < 4; ++r) {
      const int gr = rbg + kg * 4 + r;
      float v = fmaxf(acc[ct][r] + bv, 0.f) + bf2f(X0[(size_t)gr * 256 + col]);
      Y[1][rbl + kg * 4 + r][col] = f2bf(v);
    }
  }
  __syncthreads();
#pragma unroll
  for (int ct = 0; ct < 16; ++ct) acc[ct] = z4;
  for (int k0 = 0; k0 < 256; k0 += 32) {
    bf16x8 a = *(const bf16x8*)(&Y[1][rbl + m16][k0 + kg * 8]);
#pragma unroll
    for (int ct = 0; ct < 16; ++ct)
      acc[ct] = MFMA16(a, ld8(w3T + (ct * 16 + m16) * 256 + k0 + kg * 8), acc[ct]);
  }
#pragma unroll
  for (int ct = 0; ct < 16; ++ct) {
    const int col = ct * 16 + m16;
    const float bv = bf2f(b3[col]);
#pragma unroll
    for (int r = 0; r < 4; ++r)
      Y[0][rbl + kg * 4 + r][col] = f2bf(fmaxf(acc[ct][r] + bv, 0.f));
  }
  __syncthreads();
#pragma unroll
  for (int ct = 0; ct < 16; ++ct) acc[ct] = z4;
  for (int k0 = 0; k0 < 256; k0 += 32) {
    bf16x8 a = *(const bf16x8*)(&Y[0][rbl + m16][k0 + kg * 8]);
#pragma unroll
    for (int ct = 0; ct < 16; ++ct)
      acc[ct] = MFMA16(a, ld8(w4T + (ct * 16 + m16) * 256 + k0 + kg * 8), acc[ct]);
  }
  float ssq[4] = {0.f, 0.f, 0.f, 0.f};
#pragma unroll
  for (int ct = 0; ct < 16; ++ct) {
    const int col = ct * 16 + m16;
    const float bv = bf2f(b4[col]);
#pragma unroll
    for (int r = 0; r < 4; ++r) {
      const int rl = rbl + kg * 4 + r;
      float v = fmaxf(acc[ct][r] + bv, 0.f) + bf2f(Y[1][rl][col]);
      ssq[r] += v * v;
      FT[(size_t)(rbg + kg * 4 + r) * 256 + col] = f2bf(v);
    }
  }
#pragma unroll
  for (int r = 0; r < 4; ++r) {
    float s = ssq[r];
#pragma unroll
    for (int mk = 1; mk < 16; mk <<= 1) s += __shfl_xor(s, mk, 64);
    if (m16 == 0) rs_ft[rbg + kg * 4 + r] = rsqrtf(s);
  }
}

// ---------------- feature bodies ----------------
__device__ void feat_body(const u16* __restrict__ X, const float* __restrict__ rscale,
                          const u16* __restrict__ PT, u16* __restrict__ OUT, int blk,
                          float* __restrict__ SBNpart) {
  __shared__ float cred[128];
  const int tid = threadIdx.x, lane = tid & 63, w = tid >> 6;
  const int m16 = lane & 15, kg = lane >> 4;
  const int rb = blk * 64 + w * 16;
  if (SBNpart) {
    if (tid < 128) cred[tid] = 0.f;
    __syncthreads();
  }
  const floatx4 z4 = {0.f, 0.f, 0.f, 0.f};
  floatx4 acc[8];
#pragma unroll
  for (int ct = 0; ct < 8; ++ct) acc[ct] = z4;
  for (int k0 = 0; k0 < 256; k0 += 32) {
    bf16x8 a = ld8(X + (size_t)(rb + m16) * 256 + k0 + kg * 8);
#pragma unroll
    for (int ct = 0; ct < 8; ++ct)
      acc[ct] = MFMA16(a, ld8(PT + (ct * 16 + m16) * 256 + k0 + kg * 8), acc[ct]);
  }
  float rs[4];
#pragma unroll
  for (int r = 0; r < 4; ++r) rs[r] = rscale[rb + kg * 4 + r];
#pragma unroll
  for (int ct = 0; ct < 8; ++ct) {
    float s = 0.f;
#pragma unroll
    for (int r = 0; r < 4; ++r) {
      float v = expf(acc[ct][r] * rs[r]);
      s += v;
      OUT[(size_t)(rb + kg * 4 + r) * 128 + ct * 16 + m16] = f2bf(v);
    }
    if (SBNpart) atomicAdd(&cred[ct * 16 + m16], s);
  }
  if (SBNpart) {
    __syncthreads();
    if (tid < 128) SBNpart[(size_t)blk * 128 + tid] = cred[tid];
  }
}

__device__ void gather_body(const int* __restrict__ text, const u16* __restrict__ TE,
                            const float* __restrict__ rs_term, const u16* __restrict__ PT,
                            u16* __restrict__ Btok, int blk) {
  const int tid = threadIdx.x, lane = tid & 63, w = tid >> 6;
  const int m16 = lane & 15, kg = lane >> 4;
  const int rb = blk * 64 + w * 16;
  const int ia = rb + m16;
  const int tok_a = text[(ia & 15) * 256 + (ia >> 4)];
  const floatx4 z4 = {0.f, 0.f, 0.f, 0.f};
  floatx4 acc[8];
#pragma unroll
  for (int ct = 0; ct < 8; ++ct) acc[ct] = z4;
  for (int k0 = 0; k0 < 256; k0 += 32) {
    bf16x8 a = ld8(TE + (size_t)tok_a * 256 + k0 + kg * 8);
#pragma unroll
    for (int ct = 0; ct < 8; ++ct)
      acc[ct] = MFMA16(a, ld8(PT + (ct * 16 + m16) * 256 + k0 + kg * 8), acc[ct]);
  }
  float rs[4];
#pragma unroll
  for (int r = 0; r < 4; ++r) {
    const int io = rb + kg * 4 + r;
    rs[r] = rs_term[text[(io & 15) * 256 + (io >> 4)]];
  }
#pragma unroll
  for (int ct = 0; ct < 8; ++ct)
#pragma unroll
    for (int r = 0; r < 4; ++r)
      Btok[(size_t)(rb + kg * 4 + r) * 128 + ct * 16 + m16] = f2bf(expf(acc[ct][r] * rs[r]));
}

__device__ void colsum_body(const u16* __restrict__ X, const float* __restrict__ rscale,
                            const u16* __restrict__ PT, float* __restrict__ part, int blk) {
  __shared__ float cred2[128];
  const int tid = threadIdx.x, lane = tid & 63, w = tid >> 6;
  const int m16 = lane & 15, kg = lane >> 4;
  const int rb = blk * 64 + w * 16;
  if (tid < 128) cred2[tid] = 0.f;
  __syncthreads();
  const floatx4 z4 = {0.f, 0.f, 0.f, 0.f};
  floatx4 acc[8];
#pragma unroll
  for (int ct = 0; ct < 8; ++ct) acc[ct] = z4;
  for (int k0 = 0; k0 < 256; k0 += 32) {
    bf16x8 a = ld8(X + (size_t)(rb + m16) * 256 + k0 + kg * 8);
#pragma unroll
    for (int ct = 0; ct < 8; ++ct)
      acc[ct] = MFMA16(a, ld8(PT + (ct * 16 + m16) * 256 + k0 + kg * 8), acc[ct]);
  }
  float rs[4];
#pragma unroll
  for (int r = 0; r < 4; ++r) rs[r] = rscale[rb + kg * 4 + r];
#pragma unroll
  for (int ct = 0; ct < 8; ++ct) {
    float s = 0.f;
#pragma unroll
    for (int r = 0; r < 4; ++r) s += expf(acc[ct][r] * rs[r]);
    atomicAdd(&cred2[ct * 16 + m16], s);
  }
  __syncthreads();
  if (tid < 128) part[(size_t)blk * 128 + tid] = cred2[tid];
}

__device__ void start_body(
    const u16* se, const u16* sw0, const u16* sb0, const u16* sw1, const u16* sb1,
    const u16* sw2, const u16* sb2, const u16* sw3, const u16* sb3,
    const u16* sw4, const u16* sb4, const u16* proj, float* ex0) {
  __shared__ float xa[256], xb[256], xc[256], red[256];
  const int tid = threadIdx.x;
  xa[tid] = bf2f(se[tid]);
  __syncthreads();
  float acc = bf2f(sb0[tid]);
  for (int k = 0; k < 256; ++k) acc += xa[k] * bf2f(sw0[k * 256 + tid]);
  xb[tid] = acc;
  __syncthreads();
  acc = bf2f(sb1[tid]);
  for (int k = 0; k < 256; ++k) acc += xb[k] * bf2f(sw1[k * 256 + tid]);
  xc[tid] = fmaxf(acc, 0.f);
  __syncthreads();
  acc = bf2f(sb2[tid]);
  for (int k = 0; k < 256; ++k) acc += xc[k] * bf2f(sw2[k * 256 + tid]);
  xa[tid] = fmaxf(acc, 0.f) + xb[tid];
  __syncthreads();
  acc = bf2f(sb3[tid]);
  for (int k = 0; k < 256; ++k) acc += xa[k] * bf2f(sw3[k * 256 + tid]);
  xc[tid] = fmaxf(acc, 0.f);
  __syncthreads();
  acc = bf2f(sb4[tid]);
  for (int k = 0; k < 256; ++k) acc += xc[k] * bf2f(sw4[k * 256 + tid]);
  xb[tid] = fmaxf(acc, 0.f) + xa[tid];
  __syncthreads();
  red[tid] = xb[tid] * xb[tid];
  __syncthreads();
  for (int s = 128; s > 0; s >>= 1) {
    if (tid < s) red[tid] += red[tid + s];
    __syncthreads();
  }
  const float rs = rsqrtf(red[0]);
  xa[tid] = xb[tid] * rs;
  __syncthreads();
  if (tid < 128) {
    float a = 0.f;
    for (int k = 0; k < 256; ++k) a += xa[k] * bf2f(proj[k * 128 + tid]);
    ex0[tid] = expf(a);
  }
}

__global__ __launch_bounds__(256) void k_featall(
    const u16* __restrict__ c_state, const float* __restrict__ rs_state, u16* __restrict__ AxS,
    const u16* __restrict__ c_next, const float* __restrict__ rs_next, u16* __restrict__ ByN,
    float* __restrict__ SBNpart,
    const u16* __restrict__ ft, const float* __restrict__ rs_ft, u16* __restrict__ AxP,
    const int* __restrict__ text, const u16* __restrict__ c_term,
    const float* __restrict__ rs_term, u16* __restrict__ Btok,
    float* __restrict__ SBTpart, const u16* __restrict__ PT,
    const u16* c_se, const u16* sw0, const u16* sb0, const u16* sw1, const u16* sb1,
    const u16* sw2, const u16* sb2, const u16* sw3, const u16* sb3,
    const u16* sw4, const u16* sb4, const u16* c_proj, float* ex0) {
  const int b = blockIdx.x;
  if (b < 64) feat_body(c_state, rs_state, PT, AxS, b, nullptr);
  else if (b < 128) feat_body(c_next, rs_next, PT, ByN, b - 64, SBNpart);
  else if (b < 192) feat_body(ft, rs_ft, PT, AxP, b - 128, nullptr);
  else if (b < 256) gather_body(text, c_term, rs_term, PT, Btok, b - 192);
  else if (b < 756) colsum_body(c_term, rs_term, PT, SBTpart, b - 256);
  else start_body(c_se, sw0, sb0, sw1, sb1, sw2, sb2, sw3, sb3, sw4, sb4, c_proj, ex0);
}

// ---------------- 2-job partial reduction ----------------
__global__ void k_colred2(const float* __restrict__ SBTpart, const float* __restrict__ SBNpart,
                          float* __restrict__ SBT, float* __restrict__ SBN) {
  const int tid = threadIdx.x;
  if (tid >= 128) return;
  if (blockIdx.x == 0) {
    float s = 0.f;
    for (int b = 0; b < 500; ++b) s += SBTpart[(size_t)b * 128 + tid];
    SBT[tid] = s;
  } else {
    float s = 0.f;
    for (int b = 0; b < 64; ++b) s += SBNpart[(size_t)b * 128 + tid];
    SBN[tid] = s;
  }
}

// ---------------- per-state scalars ----------------
__global__ __launch_bounds__(256) void k_vecdots(
    const u16* __restrict__ AxS, const u16* __restrict__ AxP, const u16* __restrict__ ByN,
    const float* __restrict__ SBN, const float* __restrict__ SBT, const float* __restrict__ ex0,
    float* __restrict__ recip_r, float* __restrict__ recip_den,
    float* __restrict__ start_raw) {
  const int w = threadIdx.x >> 6, lane = threadIdx.x & 63;
  const int c = blockIdx.x * 4 + w;
  const int d = lane * 2;
  float a0 = bf2f(AxS[(size_t)c * 128 + d]), a1 = bf2f(AxS[(size_t)c * 128 + d + 1]);
  float t = wred64(a0 * SBN[d] + a1 * SBN[d + 1]);
  float p0 = bf2f(AxP[(size_t)c * 128 + d]), p1 = bf2f(AxP[(size_t)c * 128 + d + 1]);
  float p = wred64(p0 * SBT[d] + p1 * SBT[d + 1]);
  float y0 = bf2f(ByN[(size_t)c * 128 + d]), y1 = bf2f(ByN[(size_t)c * 128 + d + 1]);
  float s = wred64(y0 * ex0[d] + y1 * ex0[d + 1]);
  if (lane == 0) {
    recip_r[c] = 1.0f / t;
    recip_den[c] = 1.0f / p;
    start_raw[c] = s;
  }
}

// ---------------- EMr blocked layout ----------------
__global__ __launch_bounds__(256) void k_pair(const u16* __restrict__ A, const u16* __restrict__ B,
                                              const float* __restrict__ cscale,
                                              u16* __restrict__ EMr) {
  const int tid = threadIdx.x, lane = tid & 63, w = tid >> 6;
  const int m16 = lane & 15, kg = lane >> 4;
  const int mb = blockIdx.y * 128 + w * 32;
  const int nb = blockIdx.x * 128;
  const floatx4 z4 = {0.f, 0.f, 0.f, 0.f};
  floatx4 acc[2][8];
#pragma unroll
  for (int rt = 0; rt < 2; ++rt)
#pragma unroll
    for (int ct = 0; ct < 8; ++ct) acc[rt][ct] = z4;
  for (int k0 = 0; k0 < 128; k0 += 32) {
    bf16x8 a0 = ld8(A + (size_t)(mb + m16) * 128 + k0 + kg * 8);
    bf16x8 a1 = ld8(A + (size_t)(mb + 16 + m16) * 128 + k0 + kg * 8);
#pragma unroll
    for (int ct = 0; ct < 8; ++ct) {
      bf16x8 bb = ld8(B + (size_t)(nb + ct * 16 + m16) * 128 + k0 + kg * 8);
      acc[0][ct] = MFMA16(a0, bb, acc[0][ct]);
      acc[1][ct] = MFMA16(a1, bb, acc[1][ct]);
    }
  }
  float cs[8];
#pragma unroll
  for (int ct = 0; ct < 8; ++ct) cs[ct] = cscale[nb + ct * 16 + m16];
#pragma unroll
  for (int rt = 0; rt < 2; ++rt)
#pragma unroll
    for (int ct = 0; ct < 8; ++ct)
#pragma unroll
      for (int r = 0; r < 4; ++r) {
        const int row = mb + rt * 16 + kg * 4 + r;  // nt
        const int col = nb + ct * 16 + m16;         // c
        const int t = row >> 4, n = row & 15;
        const size_t idx = ((size_t)(col >> 8) * 256 + t) * 4096 + n * 256 + (col & 255);
        EMr[idx] = f2bf(acc[rt][ct][r] * cs[ct]);
      }
}

// ---------------- persistent 16-block scan, private-slot barrier ----------------
// Slot (t,b): bf16 v[16][128] (4096B) @0 | f32 S[16] (64B) @4096; stride 4352B.
#define SLOT 4352
__global__ __launch_bounds__(256) void k_scan(
    const u16* __restrict__ EMr, const u16* __restrict__ ByN, const u16* __restrict__ AxS,
    const float* __restrict__ recip_r, const float* __restrict__ start_raw,
    char* __restrict__ VS, u32* __restrict__ flags,
    float* __restrict__ ssum_s, const int* __restrict__ flag, u16* __restrict__ outp) {
  __shared__ __align__(16) u16 ByNs[256][132];
  __shared__ __align__(16) u16 AxS2s[128][260];
  __shared__ __align__(16) u16 ush[16][264];
  __shared__ __align__(16) u16 vsh[16][136];
  __shared__ __align__(16) char emtbuf[8448];  // emt u16[16][264] | vout f32[16][128]
  __shared__ float red2[256];
  __shared__ int timeout_sh;
  u16(*emt)[264] = (u16(*)[264])emtbuf;
  float(*vout)[128] = (float(*)[128])emtbuf;
  const int tid = threadIdx.x, lane = tid & 63, w = tid >> 6;
  const int m16 = lane & 15, kg = lane >> 4;
  const int b = blockIdx.x, cb = b * 256;
  const int n1 = tid >> 4, d8 = (tid & 15) * 8;
  const floatx4 z4 = {0.f, 0.f, 0.f, 0.f};

  if (tid == 0) timeout_sh = 0;
  // stage ByN slice
  for (int i = tid; i < 4096; i += 256) {
    const int r = i >> 4, c8 = (i & 15) * 8;
    *(uint4*)(&ByNs[r][c8]) = *(const uint4*)(ByN + (size_t)(cb + r) * 128 + c8);
  }
  // stage AxS2 slice (fold recip_r, transpose in LDS)
  {
    const float rr = recip_r[cb + tid];
    const u16* arow = AxS + (size_t)(cb + tid) * 128;
    for (int e8 = 0; e8 < 128; e8 += 8) {
      bf16x8 a = ld8(arow + e8);
#pragma unroll
      for (int j = 0; j < 8; ++j) AxS2s[e8 + j][tid] = f2bf((float)a[j] * rr);
    }
  }
  // ssum partial
  {
    float s = wred64(start_raw[cb + tid]);
    if (lane == 0) atomicAdd(ssum_s, s);
  }
  // t=0 EM tile
  {
    const u16* g0 = EMr + (size_t)(b * 256) * 4096;
    uint4 e0 = *(const uint4*)(g0 + tid * 8), e1 = *(const uint4*)(g0 + (tid + 256) * 8);
    *(uint4*)(&emt[tid >> 5][(tid & 31) * 8]) = e0;
    *(uint4*)(&emt[(tid + 256) >> 5][((tid + 256) & 31) * 8]) = e1;
  }
  __syncthreads();
  // t=0: u0 = start_raw * EM0
  {
    const int n0 = tid >> 4, cg0 = tid & 15;
    float s0 = 0.f;
#pragma unroll
    for (int j = 0; j < 16; ++j) {
      const int c = cg0 * 16 + j;
      float u = start_raw[cb + c] * bf2f(emt[n0][c]);
      ush[n0][c] = f2bf(u);
      s0 += u;
    }
    red2[tid] = s0;
  }
  __syncthreads();
  // contract u0 -> vout
#pragma unroll
  for (int ct2 = 0; ct2 < 2; ++ct2) {
    const int ct = w * 2 + ct2;
    floatx4 acc = z4;
#pragma unroll
    for (int k0 = 0; k0 < 256; k0 += 32)
      acc = MFMA16(*(const bf16x8*)(&ush[m16][k0 + kg * 8]),
                   *(const bf16x8*)(&AxS2s[ct * 16 + m16][k0 + kg * 8]), acc);
#pragma unroll
    for (int r = 0; r < 4; ++r) vout[kg * 4 + r][ct * 16 + m16] = acc[r];
  }
  __syncthreads();
  // publish slot 0
  {
    char* slot = VS + (size_t)b * SLOT;
    u16 tmp[8];
#pragma unroll
    for (int j = 0; j < 8; ++j) tmp[j] = f2bf(vout[n1][d8 + j]);
    u64* dst = (u64*)(slot + n1 * 256 + d8 * 2);
    u64 q[2]; __builtin_memcpy(q, tmp, 16);
    AST(dst, q[0]); AST(dst + 1, q[1]);
    if (tid < 16) {
      float S = 0.f;
#pragma unroll
      for (int j = 0; j < 16; ++j) S += red2[tid * 16 + j];
      AST((float*)(slot + 4096 + tid * 4), S);
    }
  }
  __threadfence();
  __syncthreads();
  if (tid == 0)
    __hip_atomic_store(&flags[b], 1u, __ATOMIC_RELEASE, __HIP_MEMORY_SCOPE_AGENT);

  // ---- main loop ----
  for (int t = 1; t < 256; ++t) {
    const u16* g = EMr + (size_t)(b * 256 + t) * 4096;
    uint4 e0 = *(const uint4*)(g + tid * 8);
    uint4 e1 = *(const uint4*)(g + (tid + 256) * 8);
    // barrier: 16 lanes poll per-block flags of step t-1
    if (w == 0) {
      long it = 0;
      int mydone = (lane >= 16);
      while (!__all(mydone)) {
        if (lane < 16 && !mydone)
          mydone = (__hip_atomic_load(&flags[(t - 1) * 16 + lane], __ATOMIC_ACQUIRE,
                                      __HIP_MEMORY_SCOPE_AGENT) == (u32)t);
        __builtin_amdgcn_s_sleep(1);
        if (++it > 10000000L) { if (lane == 0) timeout_sh = 1; break; }
      }
    }
    __syncthreads();  // [A]
    if (timeout_sh) break;
    // read 16 slots: v-partials (2x8B each) + S-partials (this lane's n1)
    float vv[8] = {0.f, 0.f, 0.f, 0.f, 0.f, 0.f, 0.f, 0.f};
    float Ssum = 0.f;
    {
      const char* base = VS + (size_t)(t - 1) * 16 * SLOT;
#pragma unroll
      for (int s = 0; s < 16; ++s) {
        const char* slot = base + (size_t)s * SLOT;
        const u64* vp = (const u64*)(slot + n1 * 256 + d8 * 2);
        u64 q0 = ALD(vp), q1 = ALD(vp + 1);
        u16 h[8]; __builtin_memcpy(h, &q0, 8); __builtin_memcpy(h + 4, &q1, 8);
#pragma unroll
        for (int j = 0; j < 8; ++j) vv[j] += bf2f(h[j]);
        Ssum += ALD((const float*)(slot + 4096 + n1 * 4));
      }
    }
    // EM tile -> LDS; vsh = normalized v
    *(uint4*)(&emt[tid >> 5][(tid & 31) * 8]) = e0;
    *(uint4*)(&emt[(tid + 256) >> 5][((tid + 256) & 31) * 8]) = e1;
    {
      const float rS = 1.0f / Ssum;
      u16 tmp[8];
#pragma unroll
      for (int j = 0; j < 8; ++j) tmp[j] = f2bf(vv[j] * rS);
      *(uint4*)(&vsh[n1][d8]) = *(uint4*)tmp;
    }
    __syncthreads();  // [D]
    // expand: u[n][c] = (v·ByN[c]) * EM[t][n][c]
#pragma unroll
    for (int ct2 = 0; ct2 < 4; ++ct2) {
      const int ct = w * 4 + ct2;
      floatx4 acc = z4;
#pragma unroll
      for (int k0 = 0; k0 < 128; k0 += 32)
        acc = MFMA16(*(const bf16x8*)(&vsh[m16][k0 + kg * 8]),
                     *(const bf16x8*)(&ByNs[ct * 16 + m16][k0 + kg * 8]), acc);
#pragma unroll
      for (int r = 0; r < 4; ++r)
        ush[kg * 4 + r][ct * 16 + m16] =
            f2bf(acc[r] * bf2f(emt[kg * 4 + r][ct * 16 + m16]));
    }
    __syncthreads();  // [E]
    // S partial
    {
      const int n = tid >> 4, jg = tid & 15;
      float s = 0.f;
#pragma unroll
      for (int k = 0; k < 16; ++k) s += bf2f(ush[n][jg * 16 + k]);
      red2[tid] = s;
    }
    // contract -> vout (emt dead after [E])
#pragma unroll
    for (int ct2 = 0; ct2 < 2; ++ct2) {
      const int ct = w * 2 + ct2;
      floatx4 acc = z4;
#pragma unroll
      for (int k0 = 0; k0 < 256; k0 += 32)
        acc = MFMA16(*(const bf16x8*)(&ush[m16][k0 + kg * 8]),
                     *(const bf16x8*)(&AxS2s[ct * 16 + m16][k0 + kg * 8]), acc);
#pragma unroll
      for (int r = 0; r < 4; ++r) vout[kg * 4 + r][ct * 16 + m16] = acc[r];
    }
    __syncthreads();  // [G]
    // publish slot t
    {
      char* slot = VS + ((size_t)t * 16 + b) * SLOT;
      u16 tmp[8];
#pragma unroll
      for (int j = 0; j < 8; ++j) tmp[j] = f2bf(vout[n1][d8 + j]);
      u64* dst = (u64*)(slot + n1 * 256 + d8 * 2);
      u64 q[2]; __builtin_memcpy(q, tmp, 16);
      AST(dst, q[0]); AST(dst + 1, q[1]);
      if (tid < 16) {
        float S = 0.f;
#pragma unroll
        for (int j = 0; j < 16; ++j) S += red2[tid * 16 + j];
        AST((float*)(slot + 4096 + tid * 4), S);
      }
    }
    __threadfence();
    __syncthreads();  // [H]
    if (tid == 0)
      __hip_atomic_store(&flags[t * 16 + b], (u32)(t + 1), __ATOMIC_RELEASE,
                         __HIP_MEMORY_SCOPE_AGENT);
  }

  // ---- finalize: block 0 re-reads all S slots, sums log S ----
  if (b == 0) {
    if (w == 0 && !timeout_sh) {
      long it = 0;
      int mydone = (lane >= 16);
      while (!__all(mydone)) {
        if (lane < 16 && !mydone)
          mydone = (__hip_atomic_load(&flags[255 * 16 + lane], __ATOMIC_ACQUIRE,
                                      __HIP_MEMORY_SCOPE_AGENT) == 256u);
        __builtin_amdgcn_s_sleep(1);
        if (++it > 10000000L) { if (lane == 0) timeout_sh = 1; break; }
      }
    }
    __syncthreads();
    float lsum = 0.f;
    for (int idx = tid; idx < 4096; idx += 256) {
      const int t = idx >> 4, n = idx & 15;
      const char* base = VS + (size_t)t * 16 * SLOT;
      float S = 0.f;
#pragma unroll
      for (int s = 0; s < 16; ++s)
        S += ALD((const float*)(base + (size_t)s * SLOT + 4096 + n * 4));
      lsum += logf(S);
    }
    red2[tid] = lsum;
    __syncthreads();
    for (int st = 128; st > 0; st >>= 1) {
      if (tid < st) red2[tid] += red2[tid + st];
      __syncthreads();
    }
    if (tid == 0) {
      float ev = red2[0] - 16.0f * logf(ALD(ssum_s));
      if (timeout_sh) ev = -66666.0f;
      store_final(outp, ev, *flag);
    }
  }
}

extern "C" void kernel_launch(void* const* d_in, const int* in_sizes, int n_in,
                              void* d_out, int out_size, void* d_ws, size_t ws_size,
                              hipStream_t stream) {
  (void)out_size;
  u16* outp = (u16*)d_out;
  if (n_in != 26 || in_sizes[25] != 128 * 256) {
    k_sentinel<<<1, 1, 0, stream>>>(outp, 5000.0f + (float)n_in);
    return;
  }
  const int* text = (const int*)d_in[0];

  char* base = (char*)d_ws;
  size_t off = 0;
  auto take = [&](size_t bytes) -> char* {
    char* p = base + off;
    off = (off + bytes + 255) & ~(size_t)255;
    return p;
  };
  int* flag = (int*)take(256);
  u16* c_se   = (u16*)take(256 * 2);
  u16* c_w[18];
  for (int i = 0; i < 18; ++i) c_w[i] = (u16*)take(((i & 1) ? 256 : 65536) * 2);
  u16* c_state = (u16*)take((size_t)1048576 * 2);
  u16* c_next  = (u16*)take((size_t)1048576 * 2);
  u16* c_pre   = (u16*)take((size_t)1048576 * 2);
  u16* c_term  = (u16*)take((size_t)8192000 * 2);
  u16* c_proj  = (u16*)take((size_t)32768 * 2);
  u16* projT  = (u16*)take(128 * 256 * 2);
  u16* twT1   = (u16*)take(65536 * 2);
  u16* twT2   = (u16*)take(65536 * 2);
  u16* twT3   = (u16*)take(65536 * 2);
  u16* twT4   = (u16*)take(65536 * 2);
  u16* ft     = (u16*)take((size_t)4096 * 256 * 2);
  float* rs_state = (float*)take(4096 * 4);
  float* rs_next  = (float*)take(4096 * 4);
  float* rs_ft    = (float*)take(4096 * 4);
  float* rs_term  = (float*)take(32000 * 4);
  u16* AxS    = (u16*)take((size_t)4096 * 128 * 2);
  u16* ByN    = (u16*)take((size_t)4096 * 128 * 2);
  u16* AxP    = (u16*)take((size_t)4096 * 128 * 2);
  u16* Btok   = (u16*)take((size_t)4096 * 128 * 2);
  u16* EMr    = (u16*)take((size_t)4096 * 4096 * 2);
  float* SBTpart = (float*)take(500 * 128 * 4);
  float* SBNpart = (float*)take(64 * 128 * 4);
  float* SBT = (float*)take(128 * 4);
  float* SBN = (float*)take(128 * 4);
  float* recip_r   = (float*)take(4096 * 4);
  float* recip_den = (float*)take(4096 * 4);
  float* start_raw = (float*)take(4096 * 4);
  float* ex0       = (float*)take(128 * 4);
  char* VS = take((size_t)256 * 16 * SLOT);  // private slots (fully written, no init)
  char* zz = take(16384 + 256);              // flags[256][16] + ssum  (zeroed)
  u32* flags = (u32*)zz;
  float* ssum_s = (float*)(zz + 16384);

  const float ws_mb = (float)(ws_size >> 20) > 900.f ? 900.f : (float)(ws_size >> 20);
  if (off > ws_size) {
    k_sentinel<<<1, 1, 0, stream>>>(outp, 1000.0f + ws_mb);
    return;
  }

  k_detect<<<1, 64, 0, stream>>>((const u32*)d_in[25], flag);
  hipMemsetAsync(zz, 0, 16384 + 256, stream);

  CvtJobs cj;
  int cb_ = 0, cjn = 0;
  auto addcvt = [&](const void* s, u16* d, int n) {
    cj.src[cjn] = s; cj.dst[cjn] = d; cj.n[cjn] = n;
    cj.bstart[cjn] = cb_; cb_ += (n + 4095) / 4096; ++cjn;
  };
  addcvt(d_in[2], c_se, 256);
  for (int i = 0; i < 18; ++i) addcvt(d_in[3 + i], c_w[i], (i & 1) ? 256 : 65536);
  addcvt(d_in[21], c_state, 1048576);
  addcvt(d_in[22], c_next, 1048576);
  addcvt(d_in[23], c_pre, 1048576);
  addcvt(d_in[24], c_term, 8192000);
  addcvt(d_in[25], c_proj, 32768);
  cj.bstart[24] = cb_;
  k_cvt_all<<<cb_, 256, 0, stream>>>(cj, flag);

  MiscJobs mj;
  mj.tsrc[0] = c_proj;  mj.tdst[0] = projT; mj.tR[0] = 256; mj.tC[0] = 128;
  mj.tsrc[1] = c_w[10]; mj.tdst[1] = twT1;  mj.tR[1] = 256; mj.tC[1] = 256;
  mj.tsrc[2] = c_w[12]; mj.tdst[2] = twT2;  mj.tR[2] = 256; mj.tC[2] = 256;
  mj.tsrc[3] = c_w[14]; mj.tdst[3] = twT3;  mj.tR[3] = 256; mj.tC[3] = 256;
  mj.tsrc[4] = c_w[16]; mj.tdst[4] = twT4;  mj.tR[4] = 256; mj.tC[4] = 256;
  int tb = 0;
  for (int j = 0; j < 5; ++j) { mj.tbstart[j] = tb; tb += (mj.tR[j] * mj.tC[j]) / 1024; }
  mj.tbstart[5] = tb;
  mj.rX[0] = c_state; mj.rout[0] = rs_state; mj.rrows[0] = 4096;
  mj.rX[1] = c_next;  mj.rout[1] = rs_next;  mj.rrows[1] = 4096;
  mj.rX[2] = c_term;  mj.rout[2] = rs_term;  mj.rrows[2] = 32000;
  mj.rbstart[0] = 0; mj.rbstart[1] = 1024; mj.rbstart[2] = 2048; mj.rbstart[3] = 10048;
  k_misc<<<tb + 10048, 256, 0, stream>>>(mj);

  k_mlp<<<64, 256, 0, stream>>>(c_pre, twT1, c_w[11], twT2, c_w[13], twT3, c_w[15],
                                twT4, c_w[17], ft, rs_ft);
  k_featall<<<757, 256, 0, stream>>>(c_state, rs_state, AxS, c_next, rs_next, ByN, SBNpart,
                                     ft, rs_ft, AxP, text, c_term, rs_term, Btok,
                                     SBTpart, projT,
                                     c_se, c_w[0], c_w[1], c_w[2], c_w[3], c_w[4], c_w[5],
                                     c_w[6], c_w[7], c_w[8], c_w[9], c_proj, ex0);
  k_colred2<<<2, 128, 0, stream>>>(SBTpart, SBNpart, SBT, SBN);
  k_vecdots<<<1024, 256, 0, stream>>>(AxS, AxP, ByN, SBN, SBT, ex0, recip_r, recip_den,
                                      start_raw);
  k_pair<<<dim3(32, 32), 256, 0, stream>>>(Btok, AxP, recip_den, EMr);

  k_scan<<<16, 256, 0, stream>>>(EMr, ByN, AxS, recip_r, start_raw, VS, flags, ssum_s,
                                 flag, outp);
}